// Round 4
// baseline (195.242 us; speedup 1.0000x reference)
//
#include <hip/hip_runtime.h>
#include <math.h>

#define T_DIM 512
#define TP 8
#define NC 65            // 2*16*2 + 1 candidates
#define NJ 128
#define BLOCK 512        // 8 waves, one block per t, 2 blocks/CU
#define LOG2E 1.4426950408889634f
#define LN2   0.6931471805599453f
#define CORR_L2 8.617045f   // log2(50257/128)
#define WSTRIDE (NC * TP)   // 520 floats per t per side

__device__ __forceinline__ float i2f(int x) { return __int_as_float(x); }
__device__ __forceinline__ int   f2i(float x) { return __float_as_int(x); }

__device__ __forceinline__ int cand_v(int c, int sta, const int* s_rand, int p) {
    if (c == 32) return sta;
    const int cc = (c < 32) ? c : (c - 33);
    const int h = cc >> 1;
    const int r = (sta ^ (1 << h)) ^ (s_rand[cc * TP + p] & ((1 << h) - 1));
    return (c < 32) ? r : -r;
}

// one cro z-term (log2 domain): z = u*A + C
#define CRO_Z(va, vs, X) ({                                             \
    const int _x = (va) ^ (X).x;                                        \
    const float _u0 = fmaf((float)__clz(_x + 1), 0.0625f, -1.0f);       \
    const float _u = i2f(f2i(_u0) ^ ((vs) ^ (X).y));                    \
    fmaf(_u, i2f((X).w), i2f((X).z));                                   \
})

__device__ __forceinline__ float cro_body1(int va, int vs, const int4* pc, float M) {
    const int4 x0 = pc[0];
    const float z0 = CRO_Z(va, vs, x0) - M;
    float s0 = __builtin_amdgcn_exp2f(z0);
    const int4 x1 = pc[8];
    float s1 = __builtin_amdgcn_exp2f(CRO_Z(va, vs, x1) - M);
    #pragma unroll 2
    for (int k = 2; k < NJ; k += 2) {
        const int4 x = pc[k * 8];
        const int4 y = pc[(k + 1) * 8];
        s0 += __builtin_amdgcn_exp2f(CRO_Z(va, vs, x) - M);
        s1 += __builtin_amdgcn_exp2f(CRO_Z(va, vs, y) - M);
    }
    const float S = fmaxf(s0 + s1, 1e-38f);
    return (__builtin_amdgcn_logf(S) - z0) * LN2;
}

// ---------------- kernel A: one t per block, grid 512, pipelined ------------
// Register-prefetch the nei tile at prologue; after consuming it, immediately
// issue the voc tile loads so they fly across the whole cos phase.
__global__ __launch_bounds__(BLOCK, 4) void cg_t(
    const int* __restrict__ sta_loc,    // (T, 8)
    const int* __restrict__ nei_loc,    // (T, 128, 8)
    const int* __restrict__ voc_loc,    // (T, 128, 8)
    const float* __restrict__ sta_emb,  // (T, 256)
    const float* __restrict__ nei_emb,  // (T, 128, 256)
    const float* __restrict__ voc_emb,  // (T, 128, 256)
    const int* __restrict__ rand_masks, // (T, 32, 8)
    float* __restrict__ wcos,           // (T, 65, 8) workspace
    float* __restrict__ wcro)           // (T, 65, 8) workspace
{
    const int t = blockIdx.x;
    const int tid = threadIdx.x;

    __shared__ int4   s_pc4[NJ * TP];    // 16 KB (cro): {qa, qsgn, C, A}
    __shared__ float  s_cspT[2][TP * 132];
    __shared__ float  s_css[2][NJ];
    __shared__ float  s_dot[NJ];
    __shared__ float  s_nn[NJ];          // reused: nei norms then voc norms
    __shared__ float  s_eu[NJ];
    __shared__ float2 s_U[TP][17];       // cos: (U1, U0), padded
    __shared__ float  s_G[TP];
    __shared__ float  s_Mpart[8 * 8];
    __shared__ float  s_ss;
    __shared__ int    s_sta[TP];
    __shared__ int    s_rand[256];
    __shared__ int    s_qs[NJ * TP];     // cos: qa | signbit per (j,p)
    __shared__ float4 s_a[64];           // sta_emb row

    // ---- prologue: stage small inputs, issue nei tile loads ----
    if (tid < 256) s_rand[tid] = rand_masks[t * 256 + tid];
    if (tid < TP)  s_sta[tid] = sta_loc[t * TP + tid];
    if (tid < 64)  s_a[tid] = ((const float4*)(sta_emb + (size_t)t * 256))[tid];

    const int half = tid >> 8;          // 0: nei side, 1: voc side
    const int li = tid & 255;
    const int4 l4 = ((const int4*)((half ? voc_loc : nei_loc)
                                   + (size_t)t * 1024))[li];
    const int4 sta4 = ((const int4*)(sta_loc + t * TP))[li & 1];

    const int g = tid >> 2, sub = tid & 3;   // 4 lanes per j-row
    const float4* np = (const float4*)(nei_emb + ((size_t)t * NJ + g) * 256);
    const float4* vp = (const float4*)(voc_emb + ((size_t)t * NJ + g) * 256);
    float4 pf[16];
    #pragma unroll
    for (int i = 0; i < 16; ++i) pf[i] = np[sub + 4 * i];

    // loc transform: qa/qsgn tables + cspT + css (both sides, in parallel)
    {
        const int j = li >> 1, ph = li & 1;
        const int sarr[4] = {sta4.x, sta4.y, sta4.z, sta4.w};
        const int parr[4] = {l4.x, l4.y, l4.z, l4.w};
        float cs4 = 0.f;
        #pragma unroll
        for (int e = 0; e < 4; ++e) {
            const int pl = parr[e];
            const int sta = sarr[e];
            const int idx = 8 * j + 4 * ph + e;
            const int qa = pl < 0 ? -pl : pl;      // <= 15 (4-bit)
            const int qsgn = pl & 0x80000000;
            const int sa = sta < 0 ? -sta : sta;
            const int x = sa ^ qa;
            const float u0 = fmaf((float)__clz(x + 1), 0.0625f, -1.0f);
            const float csp = i2f(f2i(u0) ^ ((sta ^ pl) & 0x80000000));
            if (half) ((int2*)&s_pc4[idx])[0] = make_int2(qa, qsgn);
            else      s_qs[idx] = qa | qsgn;
            s_cspT[half][(4 * ph + e) * 132 + j] = csp;
            cs4 += csp;
        }
        // pair (li, li^1) covers p 0-3 / 4-7 of the same j (exact: dyadic)
        const float cs8 = cs4 + __shfl_xor(cs4, 1);
        if (!(li & 1)) s_css[half][j] = cs8;
    }
    __syncthreads();

    // ---- P1a: consume nei tile; then immediately issue voc tile loads ----
    {
        float dd = 0.f, nn = 0.f, ss = 0.f;
        #pragma unroll
        for (int i = 0; i < 16; ++i) {
            const float4 a = s_a[sub + 4 * i];
            const float4 b = pf[i];
            nn += b.x * b.x + b.y * b.y + b.z * b.z + b.w * b.w;
            dd += a.x * b.x + a.y * b.y + a.z * b.z + a.w * b.w;
            if (g == 0) ss += a.x * a.x + a.y * a.y + a.z * a.z + a.w * a.w;
        }
        #pragma unroll
        for (int i = 0; i < 16; ++i) pf[i] = vp[sub + 4 * i];   // prefetch voc
        nn += __shfl_xor(nn, 1); nn += __shfl_xor(nn, 2);
        dd += __shfl_xor(dd, 1); dd += __shfl_xor(dd, 2);
        if (g == 0) { ss += __shfl_xor(ss, 1); ss += __shfl_xor(ss, 2); }
        if (sub == 0) {
            s_nn[g] = nn; s_dot[g] = dd;
            if (g == 0) s_ss = ss;
        }
    }
    __syncthreads();

    // ---- S0-B: eu per j ----
    if (tid < NJ) {
        const float ns = fmaxf(sqrtf(s_ss), 1e-12f);
        s_eu[tid] = s_dot[tid] / (fmaxf(sqrtf(s_nn[tid]), 1e-12f) * ns);
    }
    __syncthreads();

    // ---- S0-C: class scan -> U1/U0/G. 512 threads: (p, chunk, q) ----
    {
        const int p = tid >> 6;                 // one p per wave
        const int chunk = (tid >> 4) & 3;
        const int q = tid & 15;
        float u1 = 0.f, u0 = 0.f, gg = 0.f;
        const int jb = chunk * 32;
        #pragma unroll 4
        for (int i = 0; i < 32; ++i) {
            const int j = jb + i;
            const int qs = s_qs[j * TP + p];
            const float csp = s_cspT[0][p * 132 + j];
            const float b = s_css[0][j] - csp;
            const float eu = s_eu[j];
            const float B = fmaf(b, 0.125f, -eu);
            const float w = fabsf(eu);
            const float wB = w * B;
            gg = fmaf(wB, B, gg);
            const bool hit = (qs & 15) == q;
            u1 += hit ? i2f(f2i(wB) ^ (qs & 0x80000000)) : 0.f;
            u0 += hit ? w : 0.f;
        }
        // reduce over chunk (bits 4-5): stays intra-wave, q preserved
        u1 += __shfl_xor(u1, 16); u1 += __shfl_xor(u1, 32);
        u0 += __shfl_xor(u0, 16); u0 += __shfl_xor(u0, 32);
        gg += __shfl_xor(gg, 16); gg += __shfl_xor(gg, 32);
        if (chunk == 0) {
            s_U[p][q] = make_float2(u1, u0);
            if (q == 0) s_G[p] = gg;
        }
    }
    __syncthreads();

    // ---- S0-D: eval 65 candidates x 8 p (collapsed 16-term sum) ----
    for (int item = tid; item < NC * TP; item += BLOCK) {
        const int c = item >> 3, p = item & 7;
        const int v = cand_v(c, s_sta[p], s_rand, p);
        const int va = v < 0 ? -v : v;
        const int svb = v & 0x80000000;
        float S1 = 0.f, S0 = 0.f;
        #pragma unroll
        for (int q = 0; q < 16; ++q) {
            const float2 uv = s_U[p][q];
            const int x = va ^ q;
            const float m = fmaf((float)__clz(x + 1), 0.0625f, -1.0f);
            S1 = fmaf(m, uv.x, S1);
            S0 = fmaf(m * m, uv.y, S0);
        }
        wcos[t * WSTRIDE + c * TP + p] =
            (s_G[p] + i2f(f2i(0.25f * S1) ^ svb) + 0.015625f * S0) * 0.0078125f;
    }

    // ---- P1b: consume voc tile (prefetched across the whole S0 phase) ----
    // Safe without a barrier: S0 phases no longer read s_nn (only s_eu/s_U).
    {
        float nn = 0.f;
        #pragma unroll
        for (int i = 0; i < 16; ++i) {
            const float4 b = pf[i];
            nn += b.x * b.x + b.y * b.y + b.z * b.z + b.w * b.w;
        }
        nn += __shfl_xor(nn, 1); nn += __shfl_xor(nn, 2);
        if (sub == 0) s_nn[g] = nn;
    }
    __syncthreads();

    // ---- S1-P4: repack {C, A}; per-(wave,p) max of (C + A) ----
    {
        const float ns = sqrtf(s_ss);
        float mloc = -INFINITY;
        #pragma unroll
        for (int k = 0; k < 2; ++k) {
            const int item = tid + k * BLOCK;   // 0..1023, p invariant
            const int j = item >> 3;
            const int p = item & 7;
            const float csp = s_cspT[1][p * 132 + j];
            const float b = s_css[1][j] - csp;
            const float A = ns * sqrtf(s_nn[j]) * (0.125f * LOG2E);
            const float z2 = fmaf(b, A, j ? CORR_L2 : 0.0f);
            mloc = fmaxf(mloc, z2 + A);
            ((int2*)&s_pc4[item])[1] = make_int2(f2i(z2), f2i(A));
        }
        mloc = fmaxf(mloc, __shfl_xor(mloc, 8));
        mloc = fmaxf(mloc, __shfl_xor(mloc, 16));
        mloc = fmaxf(mloc, __shfl_xor(mloc, 32));
        if ((tid & 63) < 8) s_Mpart[(tid >> 6) * 8 + (tid & 7)] = mloc;
    }
    __syncthreads();

    // ---- S1-P5: 65 candidates x 8 p, LDS-stream logsumexp ----
    for (int item = tid; item < NC * TP; item += BLOCK) {
        const int c = item >> 3, p = item & 7;
        const int v = cand_v(c, s_sta[p], s_rand, p);
        float M = s_Mpart[p];
        #pragma unroll
        for (int wv = 1; wv < 8; ++wv) M = fmaxf(M, s_Mpart[wv * 8 + p]);
        wcro[t * WSTRIDE + c * TP + p] =
            cro_body1(v < 0 ? -v : v, v & 0x80000000, s_pc4 + p, M);
    }
}

// ---------------- kernel B: argmin (first-min) + gather + means --------------
__global__ void cg_combine(
    const int* __restrict__ sta_loc,
    const int* __restrict__ rand_masks,
    const float* __restrict__ wcos,
    const float* __restrict__ wcro,
    float* __restrict__ out)
{
    const int t = blockIdx.x;
    const int tid = threadIdx.x;        // 64
    const int p = tid & 7, cg = tid >> 3;

    float best = INFINITY, blc = 0.f, blr = 0.f;
    int bc = NC;
    for (int c = cg; c < NC; c += 8) {  // ascending c: strict < keeps first-min
        const float lc = wcos[t * WSTRIDE + c * TP + p];
        const float lr = wcro[t * WSTRIDE + c * TP + p];
        const float lt = fmaf(0.1f, lr, lc);
        if (lt < best) { best = lt; bc = c; blc = lc; blr = lr; }
    }
    // reduce across the 8 cg-lanes sharing p; tie -> smallest c (first-min)
    #pragma unroll
    for (int d = 8; d < 64; d <<= 1) {
        const float o_best = __shfl_xor(best, d);
        const float o_blc  = __shfl_xor(blc, d);
        const float o_blr  = __shfl_xor(blr, d);
        const int   o_bc   = __shfl_xor(bc, d);
        if (o_best < best || (o_best == best && o_bc < bc)) {
            best = o_best; bc = o_bc; blc = o_blc; blr = o_blr;
        }
    }

    float vc = 0.f, vr = 0.f, vt = 0.f;
    if (tid < TP) {
        const int sta = sta_loc[t * TP + tid];
        out[t * TP + tid] = (float)cand_v(bc, sta, rand_masks + t * 256, tid);
        vc = blc; vr = blr; vt = best;
    }
    vc += __shfl_xor(vc, 1); vc += __shfl_xor(vc, 2); vc += __shfl_xor(vc, 4);
    vr += __shfl_xor(vr, 1); vr += __shfl_xor(vr, 2); vr += __shfl_xor(vr, 4);
    vt += __shfl_xor(vt, 1); vt += __shfl_xor(vt, 2); vt += __shfl_xor(vt, 4);
    if (tid == 0) {
        out[T_DIM * TP + t] = vc * 0.125f;
        out[T_DIM * TP + T_DIM + t] = vr * 0.125f;
        out[T_DIM * TP + 2 * T_DIM + t] = vt * 0.125f;
    }
}

extern "C" void kernel_launch(void* const* d_in, const int* in_sizes, int n_in,
                              void* d_out, int out_size, void* d_ws, size_t ws_size,
                              hipStream_t stream) {
    const int* sta_loc = (const int*)d_in[0];
    const int* nei_loc = (const int*)d_in[1];
    const int* voc_loc = (const int*)d_in[2];
    const float* sta_emb = (const float*)d_in[3];
    const float* nei_emb = (const float*)d_in[4];
    const float* voc_emb = (const float*)d_in[5];
    const int* rand_masks = (const int*)d_in[6];
    float* out = (float*)d_out;

    float* wcos = (float*)d_ws;                 // 520*512*4 B = 1.06 MB
    float* wcro = wcos + (size_t)WSTRIDE * T_DIM;

    cg_t<<<T_DIM, BLOCK, 0, stream>>>(
        sta_loc, nei_loc, voc_loc, sta_emb, nei_emb, voc_emb, rand_masks,
        wcos, wcro);
    cg_combine<<<T_DIM, 64, 0, stream>>>(sta_loc, rand_masks, wcos, wcro, out);
}

// Round 5
// 184.312 us; speedup vs baseline: 1.0593x; 1.0593x over previous
//
#include <hip/hip_runtime.h>
#include <math.h>

#define T_DIM 512
#define TP 8
#define NC 65            // 2*16*2 + 1 candidates
#define NJ 128
#define BLOCK 576        // 9 waves
#define LOG2E 1.4426950408889634f
#define LN2   0.6931471805599453f
#define CORR_L2 8.617045f   // log2(50257/128)
#define WSTRIDE (NC * TP)   // 520 floats per t per side

__device__ __forceinline__ float i2f(int x) { return __int_as_float(x); }
__device__ __forceinline__ int   f2i(float x) { return __float_as_int(x); }

__device__ __forceinline__ int cand_v(int c, int sta, const int* s_rand, int p) {
    if (c == 32) return sta;
    const int cc = (c < 32) ? c : (c - 33);
    const int h = cc >> 1;
    const int r = (sta ^ (1 << h)) ^ (s_rand[cc * TP + p] & ((1 << h) - 1));
    return (c < 32) ? r : -r;
}

// one cro z-term (log2 domain): z = u*A + C
#define CRO_Z(va, vs, X) ({                                             \
    const int _x = (va) ^ (X).x;                                        \
    const float _u0 = fmaf((float)__clz(_x + 1), 0.0625f, -1.0f);       \
    const float _u = i2f(f2i(_u0) ^ ((vs) ^ (X).y));                    \
    fmaf(_u, i2f((X).w), i2f((X).z));                                   \
})

__device__ __forceinline__ float cro_body1(int va, int vs, const int4* pc, float M) {
    const int4 x0 = pc[0];
    const float z0 = CRO_Z(va, vs, x0) - M;
    float s0 = __builtin_amdgcn_exp2f(z0);
    const int4 x1 = pc[8];
    float s1 = __builtin_amdgcn_exp2f(CRO_Z(va, vs, x1) - M);
    #pragma unroll 2
    for (int k = 2; k < NJ; k += 2) {
        const int4 x = pc[k * 8];
        const int4 y = pc[(k + 1) * 8];
        s0 += __builtin_amdgcn_exp2f(CRO_Z(va, vs, x) - M);
        s1 += __builtin_amdgcn_exp2f(CRO_Z(va, vs, y) - M);
    }
    const float S = fmaxf(s0 + s1, 1e-38f);
    return (__builtin_amdgcn_logf(S) - z0) * LN2;
}

__device__ __forceinline__ void cro_body2(int vaA, int vsA, int vaB, int vsB,
                                          const int4* pc, float M, float* oA, float* oB) {
    const int4 x0 = pc[0];
    const float zA0 = CRO_Z(vaA, vsA, x0) - M;
    const float zB0 = CRO_Z(vaB, vsB, x0) - M;
    float sA0 = __builtin_amdgcn_exp2f(zA0);
    float sB0 = __builtin_amdgcn_exp2f(zB0);
    const int4 x1 = pc[8];
    float sA1 = __builtin_amdgcn_exp2f(CRO_Z(vaA, vsA, x1) - M);
    float sB1 = __builtin_amdgcn_exp2f(CRO_Z(vaB, vsB, x1) - M);
    #pragma unroll 2
    for (int k = 2; k < NJ; k += 2) {
        const int4 x = pc[k * 8];
        const int4 y = pc[(k + 1) * 8];
        sA0 += __builtin_amdgcn_exp2f(CRO_Z(vaA, vsA, x) - M);
        sB0 += __builtin_amdgcn_exp2f(CRO_Z(vaB, vsB, x) - M);
        sA1 += __builtin_amdgcn_exp2f(CRO_Z(vaA, vsA, y) - M);
        sB1 += __builtin_amdgcn_exp2f(CRO_Z(vaB, vsB, y) - M);
    }
    const float SA = fmaxf(sA0 + sA1, 1e-38f);
    const float SB = fmaxf(sB0 + sB1, 1e-38f);
    *oA = (__builtin_amdgcn_logf(SA) - zA0) * LN2;
    *oB = (__builtin_amdgcn_logf(SB) - zB0) * LN2;
}

// ---------------- kernel A: one (t, side) per block. grid 1024 ----------------
// side 0 = cos (nei): R2 staging + collapsed 16-class algebra (qa is 4-bit).
// side 1 = cro (voc): R2's shared-stream logsumexp (cro_body2), verbatim.
__global__ __launch_bounds__(BLOCK, 7) void cg_side(
    const int* __restrict__ sta_loc,    // (T, 8)
    const int* __restrict__ nei_loc,    // (T, 128, 8)
    const int* __restrict__ voc_loc,    // (T, 128, 8)
    const float* __restrict__ sta_emb,  // (T, 256)
    const float* __restrict__ nei_emb,  // (T, 128, 256)
    const float* __restrict__ voc_emb,  // (T, 128, 256)
    const int* __restrict__ rand_masks, // (T, 32, 8)
    float* __restrict__ wcos,           // (T, 65, 8) workspace
    float* __restrict__ wcro)           // (T, 65, 8) workspace
{
    const int bid = blockIdx.x;
    const int side = bid & 1;           // interleave sides across CUs
    const int t = bid >> 1;
    const int tid = threadIdx.x;

    __shared__ int4   s_pc4[NJ * TP];   // 16 KB (side1): {qa, qsgn, C, A}
    __shared__ float  s_cspT[TP * 132]; // transposed csp, padded
    __shared__ float  s_css[NJ];
    __shared__ float  s_dot[NJ];        // side0 only
    __shared__ float  s_nn[NJ];
    __shared__ float  s_Mpart[9 * 8];   // side1 only
    __shared__ float  s_ss;
    __shared__ int    s_sta[TP];
    __shared__ int    s_rand[256];
    __shared__ int    s_qs[NJ * TP];    // side0: qa | signbit per (j,p)
    __shared__ float  s_eu[NJ];         // side0
    __shared__ float2 s_U[TP][17];      // side0: (U1, U0), padded
    __shared__ float  s_G[TP];          // side0

    if (tid < 256) s_rand[tid] = rand_masks[t * 256 + tid];

    if (tid < 512) {
        // ---- P1 (waves 0-7): one emb stream, 4 lanes/row, 64B-line groups ----
        const int g = tid >> 2, sub = tid & 3;
        const float4* sp = (const float4*)(sta_emb + (size_t)t * 256);
        const float* emb = side ? voc_emb : nei_emb;
        const float4* ep = (const float4*)(emb + ((size_t)t * NJ + g) * 256);
        float dd = 0.f, nn = 0.f, ss = 0.f;
        #pragma unroll 4
        for (int i = 0; i < 16; ++i) {
            const int i4 = sub + 4 * i;            // lanes 0-3 span one 64B line
            const float4 b = ep[i4];
            nn += b.x * b.x + b.y * b.y + b.z * b.z + b.w * b.w;
            if (side == 0 || g == 0) {
                const float4 a = sp[i4];
                if (side == 0) dd += a.x * b.x + a.y * b.y + a.z * b.z + a.w * b.w;
                if (g == 0)    ss += a.x * a.x + a.y * a.y + a.z * a.z + a.w * a.w;
            }
        }
        nn += __shfl_xor(nn, 1); nn += __shfl_xor(nn, 2);
        if (side == 0) { dd += __shfl_xor(dd, 1); dd += __shfl_xor(dd, 2); }
        if (g == 0) { ss += __shfl_xor(ss, 1); ss += __shfl_xor(ss, 2); }
        if (sub == 0) {
            s_nn[g] = nn;
            if (side == 0) s_dot[g] = dd;
            if (g == 0) s_ss = ss;
        }
    } else {
        // ---- P2 (wave 8): stage this side's loc -> tables + cspT + css ----
        const int l = tid - 512;                    // 0..63
        if (l < TP) s_sta[l] = sta_loc[t * TP + l];
        const int4 sta4 = ((const int4*)(sta_loc + t * TP))[l & 1];
        const int sarr[4] = {sta4.x, sta4.y, sta4.z, sta4.w};
        const int* loc = side ? voc_loc : nei_loc;
        const int4* lp = (const int4*)(loc + (size_t)t * 1024);
        #pragma unroll
        for (int q = 0; q < 4; ++q) {
            const int4 pl4 = lp[q * 64 + l];
            const int j = q * 32 + (l >> 1);
            const int parr[4] = {pl4.x, pl4.y, pl4.z, pl4.w};
            float cs4 = 0.f;
            #pragma unroll
            for (int e = 0; e < 4; ++e) {
                const int pl = parr[e];
                const int sta = sarr[e];
                const int idx = q * 256 + 4 * l + e;   // = 8*j + p
                const int qa = pl < 0 ? -pl : pl;      // <= 15 (4-bit)
                const int qsgn = pl & 0x80000000;
                const int sa = sta < 0 ? -sta : sta;
                const int x = sa ^ qa;
                const float u0 = fmaf((float)__clz(x + 1), 0.0625f, -1.0f);
                const float csp = i2f(f2i(u0) ^ ((sta ^ pl) & 0x80000000));
                if (side) ((int2*)&s_pc4[idx])[0] = make_int2(qa, qsgn);
                else      s_qs[idx] = qa | qsgn;
                s_cspT[(4 * (l & 1) + e) * 132 + j] = csp;
                cs4 += csp;
            }
            // css: pair (l, l^1) covers p 0-3 / 4-7 of the same j (exact: dyadic)
            const float cs8 = cs4 + __shfl_xor(cs4, 1);
            if (!(l & 1)) s_css[j] = cs8;
        }
    }
    __syncthreads();

    if (side == 0) {
        // ---- S0-B: eu per j ----
        if (tid < NJ) {
            const float ns = fmaxf(sqrtf(s_ss), 1e-12f);
            s_eu[tid] = s_dot[tid] / (fmaxf(sqrtf(s_nn[tid]), 1e-12f) * ns);
        }
        __syncthreads();

        // ---- S0-C: class scan -> U1/U0/G. 512 threads: (p, chunk, q) ----
        if (tid < 512) {
            const int p = tid >> 6;                 // one p per wave
            const int chunk = (tid >> 4) & 3;
            const int q = tid & 15;
            float u1 = 0.f, u0 = 0.f, gg = 0.f;
            const int jb = chunk * 32;
            #pragma unroll 4
            for (int i = 0; i < 32; ++i) {
                const int j = jb + i;
                const int qs = s_qs[j * TP + p];
                const float csp = s_cspT[p * 132 + j];
                const float b = s_css[j] - csp;
                const float eu = s_eu[j];
                const float B = fmaf(b, 0.125f, -eu);
                const float w = fabsf(eu);
                const float wB = w * B;
                gg = fmaf(wB, B, gg);
                const bool hit = (qs & 15) == q;
                u1 += hit ? i2f(f2i(wB) ^ (qs & 0x80000000)) : 0.f;
                u0 += hit ? w : 0.f;
            }
            // reduce over chunk (bits 4-5): stays intra-wave, q preserved
            u1 += __shfl_xor(u1, 16); u1 += __shfl_xor(u1, 32);
            u0 += __shfl_xor(u0, 16); u0 += __shfl_xor(u0, 32);
            gg += __shfl_xor(gg, 16); gg += __shfl_xor(gg, 32);
            if (chunk == 0) {
                s_U[p][q] = make_float2(u1, u0);
                if (q == 0) s_G[p] = gg;
            }
        }
        __syncthreads();

        // ---- S0-D: eval 65 candidates x 8 p, 16-term collapsed sum ----
        if (tid < NC * TP) {
            const int c = tid >> 3, p = tid & 7;
            const int v = cand_v(c, s_sta[p], s_rand, p);
            const int va = v < 0 ? -v : v;
            const int svb = v & 0x80000000;
            float S1 = 0.f, S0 = 0.f;
            #pragma unroll
            for (int q = 0; q < 16; ++q) {
                const float2 uv = s_U[p][q];
                const int x = va ^ q;
                const float m = fmaf((float)__clz(x + 1), 0.0625f, -1.0f);
                S1 = fmaf(m, uv.x, S1);
                S0 = fmaf(m * m, uv.y, S0);
            }
            wcos[t * WSTRIDE + c * TP + p] =
                (s_G[p] + i2f(f2i(0.25f * S1) ^ svb) + 0.015625f * S0) * 0.0078125f;
        }
    } else {
        // ---- S1-P4: repack {C, A}; per-(wave,p) max of (C + A) ----
        {
            const float ns = sqrtf(s_ss);
            float mloc = -INFINITY;
            #pragma unroll
            for (int k = 0; k < 2; ++k) {
                const int item = tid + k * BLOCK;   // BLOCK%8==0: p invariant
                if (item < 1024) {
                    const int j = item >> 3;
                    const int p = item & 7;
                    const float csp = s_cspT[p * 132 + j];
                    const float b = s_css[j] - csp;
                    const float A = ns * sqrtf(s_nn[j]) * (0.125f * LOG2E);
                    const float z2 = fmaf(b, A, j ? CORR_L2 : 0.0f);
                    mloc = fmaxf(mloc, z2 + A);
                    ((int2*)&s_pc4[item])[1] = make_int2(f2i(z2), f2i(A));
                }
            }
            mloc = fmaxf(mloc, __shfl_xor(mloc, 8));
            mloc = fmaxf(mloc, __shfl_xor(mloc, 16));
            mloc = fmaxf(mloc, __shfl_xor(mloc, 32));
            const int lane = tid & 63;
            if (lane < 8) s_Mpart[(tid >> 6) * 8 + lane] = mloc;
        }
        __syncthreads();

        // ---- S1-P5: 2 candidates per thread sharing one LDS stream ----
        if (tid < 256) {                    // waves 0-3: c = {2gk, 2gk+1}
            const int gk = tid >> 3, p = tid & 7;
            const int sta = s_sta[p];
            const int vA = cand_v(2 * gk, sta, s_rand, p);
            const int vB = cand_v(2 * gk + 1, sta, s_rand, p);
            float M = s_Mpart[p];
            #pragma unroll
            for (int wv = 1; wv < 9; ++wv) M = fmaxf(M, s_Mpart[wv * 8 + p]);
            float oA, oB;
            cro_body2(vA < 0 ? -vA : vA, vA & 0x80000000,
                      vB < 0 ? -vB : vB, vB & 0x80000000, s_pc4 + p, M, &oA, &oB);
            wcro[t * WSTRIDE + (2 * gk) * TP + p] = oA;
            wcro[t * WSTRIDE + (2 * gk + 1) * TP + p] = oB;
        } else if (tid < 264) {             // c = 64
            const int p = tid - 256;
            const int v = cand_v(64, s_sta[p], s_rand, p);
            float M = s_Mpart[p];
            #pragma unroll
            for (int wv = 1; wv < 9; ++wv) M = fmaxf(M, s_Mpart[wv * 8 + p]);
            wcro[t * WSTRIDE + 64 * TP + p] =
                cro_body1(v < 0 ? -v : v, v & 0x80000000, s_pc4 + p, M);
        }
    }
}

// ---------------- kernel B: argmin (first-min) + gather + means --------------
__global__ void cg_combine(
    const int* __restrict__ sta_loc,
    const int* __restrict__ rand_masks,
    const float* __restrict__ wcos,
    const float* __restrict__ wcro,
    float* __restrict__ out)
{
    const int t = blockIdx.x;
    const int tid = threadIdx.x;        // 64
    const int p = tid & 7, cg = tid >> 3;

    float best = INFINITY, blc = 0.f, blr = 0.f;
    int bc = NC;
    for (int c = cg; c < NC; c += 8) {  // ascending c: strict < keeps first-min
        const float lc = wcos[t * WSTRIDE + c * TP + p];
        const float lr = wcro[t * WSTRIDE + c * TP + p];
        const float lt = fmaf(0.1f, lr, lc);
        if (lt < best) { best = lt; bc = c; blc = lc; blr = lr; }
    }
    // reduce across the 8 cg-lanes sharing p; tie -> smallest c (first-min)
    #pragma unroll
    for (int d = 8; d < 64; d <<= 1) {
        const float o_best = __shfl_xor(best, d);
        const float o_blc  = __shfl_xor(blc, d);
        const float o_blr  = __shfl_xor(blr, d);
        const int   o_bc   = __shfl_xor(bc, d);
        if (o_best < best || (o_best == best && o_bc < bc)) {
            best = o_best; bc = o_bc; blc = o_blc; blr = o_blr;
        }
    }

    float vc = 0.f, vr = 0.f, vt = 0.f;
    if (tid < TP) {
        const int sta = sta_loc[t * TP + tid];
        out[t * TP + tid] = (float)cand_v(bc, sta, rand_masks + t * 256, tid);
        vc = blc; vr = blr; vt = best;
    }
    vc += __shfl_xor(vc, 1); vc += __shfl_xor(vc, 2); vc += __shfl_xor(vc, 4);
    vr += __shfl_xor(vr, 1); vr += __shfl_xor(vr, 2); vr += __shfl_xor(vr, 4);
    vt += __shfl_xor(vt, 1); vt += __shfl_xor(vt, 2); vt += __shfl_xor(vt, 4);
    if (tid == 0) {
        out[T_DIM * TP + t] = vc * 0.125f;
        out[T_DIM * TP + T_DIM + t] = vr * 0.125f;
        out[T_DIM * TP + 2 * T_DIM + t] = vt * 0.125f;
    }
}

extern "C" void kernel_launch(void* const* d_in, const int* in_sizes, int n_in,
                              void* d_out, int out_size, void* d_ws, size_t ws_size,
                              hipStream_t stream) {
    const int* sta_loc = (const int*)d_in[0];
    const int* nei_loc = (const int*)d_in[1];
    const int* voc_loc = (const int*)d_in[2];
    const float* sta_emb = (const float*)d_in[3];
    const float* nei_emb = (const float*)d_in[4];
    const float* voc_emb = (const float*)d_in[5];
    const int* rand_masks = (const int*)d_in[6];
    float* out = (float*)d_out;

    float* wcos = (float*)d_ws;                 // 520*512*4 B = 1.06 MB
    float* wcro = wcos + (size_t)WSTRIDE * T_DIM;

    cg_side<<<2 * T_DIM, BLOCK, 0, stream>>>(
        sta_loc, nei_loc, voc_loc, sta_emb, nei_emb, voc_emb, rand_masks,
        wcos, wcro);
    cg_combine<<<T_DIM, 64, 0, stream>>>(sta_loc, rand_masks, wcos, wcro, out);
}

// Round 6
// 178.721 us; speedup vs baseline: 1.0924x; 1.0313x over previous
//
#include <hip/hip_runtime.h>
#include <math.h>

#define T_DIM 512
#define TP 8
#define NC 65            // 2*16*2 + 1 candidates
#define NJ 128
#define NCH 4            // j-chunks per (t, side)
#define CJ 32            // j rows per chunk
#define BLOCK 256        // 4 waves
#define LOG2E 1.4426950408889634f
#define LN2   0.6931471805599453f
#define CORR_L2 8.617045f   // log2(50257/128)
#define WSTRIDE (NC * TP)   // 520 items per t per side

__device__ __forceinline__ float i2f(int x) { return __int_as_float(x); }
__device__ __forceinline__ int   f2i(float x) { return __float_as_int(x); }

__device__ __forceinline__ int cand_v(int c, int sta, const int* s_rand, int p) {
    if (c == 32) return sta;
    const int cc = (c < 32) ? c : (c - 33);
    const int h = cc >> 1;
    const int r = (sta ^ (1 << h)) ^ (s_rand[cc * TP + p] & ((1 << h) - 1));
    return (c < 32) ? r : -r;
}

// one cro z-term (log2 domain): z = u*A + C
#define CRO_Z(va, vs, X) ({                                             \
    const int _x = (va) ^ (X).x;                                        \
    const float _u0 = fmaf((float)__clz(_x + 1), 0.0625f, -1.0f);       \
    const float _u = i2f(f2i(_u0) ^ ((vs) ^ (X).y));                    \
    fmaf(_u, i2f((X).w), i2f((X).z));                                   \
})

// -------- kernel A: one (t, side, j-chunk) per block. grid 4096x256 --------
// Small blocks (4 waves, ~9KB LDS) -> 8 resident/CU, continuous refill,
// staggered memory bursts. Each block streams 32KB emb + 1KB loc, computes
// chunk partials: cos (collapsed 16-class) or cro (local-M logsumexp).
__global__ __launch_bounds__(BLOCK, 8) void cg_chunk(
    const int* __restrict__ sta_loc,    // (T, 8)
    const int* __restrict__ nei_loc,    // (T, 128, 8)
    const int* __restrict__ voc_loc,    // (T, 128, 8)
    const float* __restrict__ sta_emb,  // (T, 256)
    const float* __restrict__ nei_emb,  // (T, 128, 256)
    const float* __restrict__ voc_emb,  // (T, 128, 256)
    const int* __restrict__ rand_masks, // (T, 32, 8)
    float* __restrict__ wcos,           // (NCH, T, 520) cos partials
    float* __restrict__ wS,             // (NCH, T, 520) cro partial sums
    float* __restrict__ wM,             // (NCH, T, 8)   cro chunk max
    float* __restrict__ wz0)            // (T, 520)      cro z(j=0) absolute
{
    const int bid = blockIdx.x;
    const int t = bid & (T_DIM - 1);
    const int side = (bid >> 9) & 1;
    const int chunk = bid >> 10;
    const int j0 = chunk * CJ;
    const int tid = threadIdx.x;
    const int w = tid >> 6, lane = tid & 63;
    const int jl = tid >> 3, p = tid & 7;   // one (j_local, p) per thread

    __shared__ float  s_dot[CJ];
    __shared__ float  s_nn[CJ];
    __shared__ float  s_css[CJ];
    __shared__ float  s_cspT[TP][CJ + 1];
    __shared__ float  s_eu[CJ];          // side0
    __shared__ int    s_qs[CJ * TP];     // side0: qa | signbit
    __shared__ int4   s_pc4[CJ * TP];    // side1: {qa, qsgn, C, A}
    __shared__ float2 s_U[TP][17];       // side0 tables, padded
    __shared__ float  s_G[TP];
    __shared__ float  s_Mpart[4][TP];    // side1
    __shared__ int    s_rand[256];

    s_rand[tid] = rand_masks[t * 256 + tid];

    // sta row slice (per lane) + ss (wave-redundant, ends in every register)
    const float4 a = ((const float4*)(sta_emb + (size_t)t * 256))[lane];
    float ss = a.x * a.x + a.y * a.y + a.z * a.z + a.w * a.w;
    ss += __shfl_xor(ss, 1);  ss += __shfl_xor(ss, 2);  ss += __shfl_xor(ss, 4);
    ss += __shfl_xor(ss, 8);  ss += __shfl_xor(ss, 16); ss += __shfl_xor(ss, 32);

    // emb rows for this wave: j_local = w*8 .. w*8+7, one row per wave-load
    const float* emb = side ? voc_emb : nei_emb;
    const float4* ep = (const float4*)(emb + ((size_t)t * NJ + j0 + w * 8) * 256);

    float4 bb[4];
    #pragma unroll
    for (int r = 0; r < 4; ++r) bb[r] = ep[r * 64 + lane];

    // loc transform under the load shadow
    const int sta = sta_loc[t * TP + p];
    const int pl = (side ? voc_loc : nei_loc)[t * (NJ * TP) + (j0 + jl) * TP + p];
    {
        const int qa = pl < 0 ? -pl : pl;          // <= 15 (4-bit)
        const int qsgn = pl & 0x80000000;
        const int sa = sta < 0 ? -sta : sta;
        const int x = sa ^ qa;
        const float u0 = fmaf((float)__clz(x + 1), 0.0625f, -1.0f);
        const float csp = i2f(f2i(u0) ^ ((sta ^ pl) & 0x80000000));
        if (side) ((int2*)&s_pc4[jl * TP + p])[0] = make_int2(qa, qsgn);
        else      s_qs[jl * TP + p] = qa | qsgn;
        s_cspT[p][jl] = csp;
        float cs = csp;                             // sum over p (8 lanes)
        cs += __shfl_xor(cs, 1); cs += __shfl_xor(cs, 2); cs += __shfl_xor(cs, 4);
        if (p == 0) s_css[jl] = cs;
    }

    // consume emb batch 1, issue batch 2, consume batch 2
    #pragma unroll
    for (int r = 0; r < 4; ++r) {
        const float4 b = bb[r];
        float nn = b.x * b.x + b.y * b.y + b.z * b.z + b.w * b.w;
        float dd = a.x * b.x + a.y * b.y + a.z * b.z + a.w * b.w;
        nn += __shfl_xor(nn, 1);  nn += __shfl_xor(nn, 2);  nn += __shfl_xor(nn, 4);
        nn += __shfl_xor(nn, 8);  nn += __shfl_xor(nn, 16); nn += __shfl_xor(nn, 32);
        dd += __shfl_xor(dd, 1);  dd += __shfl_xor(dd, 2);  dd += __shfl_xor(dd, 4);
        dd += __shfl_xor(dd, 8);  dd += __shfl_xor(dd, 16); dd += __shfl_xor(dd, 32);
        if (lane == 0) { s_nn[w * 8 + r] = nn; s_dot[w * 8 + r] = dd; }
    }
    #pragma unroll
    for (int r = 0; r < 4; ++r) bb[r] = ep[(4 + r) * 64 + lane];
    #pragma unroll
    for (int r = 0; r < 4; ++r) {
        const float4 b = bb[r];
        float nn = b.x * b.x + b.y * b.y + b.z * b.z + b.w * b.w;
        float dd = a.x * b.x + a.y * b.y + a.z * b.z + a.w * b.w;
        nn += __shfl_xor(nn, 1);  nn += __shfl_xor(nn, 2);  nn += __shfl_xor(nn, 4);
        nn += __shfl_xor(nn, 8);  nn += __shfl_xor(nn, 16); nn += __shfl_xor(nn, 32);
        dd += __shfl_xor(dd, 1);  dd += __shfl_xor(dd, 2);  dd += __shfl_xor(dd, 4);
        dd += __shfl_xor(dd, 8);  dd += __shfl_xor(dd, 16); dd += __shfl_xor(dd, 32);
        if (lane == 0) { s_nn[w * 8 + 4 + r] = nn; s_dot[w * 8 + 4 + r] = dd; }
    }
    __syncthreads();

    if (side == 0) {
        // ---- eu per j ----
        if (tid < CJ) {
            const float ns = fmaxf(sqrtf(ss), 1e-12f);
            s_eu[tid] = s_dot[tid] / (fmaxf(sqrtf(s_nn[tid]), 1e-12f) * ns);
        }
        __syncthreads();

        // ---- class scan -> U1/U0/G partials. (p, half, q) over 32 j ----
        {
            const int pp = tid >> 5, half = (tid >> 4) & 1, q = tid & 15;
            float u1 = 0.f, u0 = 0.f, gg = 0.f;
            #pragma unroll
            for (int i = 0; i < 16; ++i) {
                const int j = half * 16 + i;
                const int qs = s_qs[j * TP + pp];
                const float csp = s_cspT[pp][j];
                const float b = s_css[j] - csp;
                const float eu = s_eu[j];
                const float B = fmaf(b, 0.125f, -eu);
                const float ww = fabsf(eu);
                const float wB = ww * B;
                gg = fmaf(wB, B, gg);
                const bool hit = (qs & 15) == q;
                u1 += hit ? i2f(f2i(wB) ^ (qs & 0x80000000)) : 0.f;
                u0 += hit ? ww : 0.f;
            }
            u1 += __shfl_xor(u1, 16);
            u0 += __shfl_xor(u0, 16);
            gg += __shfl_xor(gg, 16);
            if (half == 0) {
                s_U[pp][q] = make_float2(u1, u0);
                if (q == 0) s_G[pp] = gg;
            }
        }
        __syncthreads();

        // ---- eval 65 candidates x 8 p: collapsed 16-term partial ----
        for (int item = tid; item < WSTRIDE; item += BLOCK) {   // p = tid&7 inv.
            const int c = item >> 3;
            const int v = cand_v(c, sta, s_rand, p);
            const int va = v < 0 ? -v : v;
            const int svb = v & 0x80000000;
            float S1 = 0.f, S0 = 0.f;
            #pragma unroll
            for (int q = 0; q < 16; ++q) {
                const float2 uv = s_U[p][q];
                const int x = va ^ q;
                const float m = fmaf((float)__clz(x + 1), 0.0625f, -1.0f);
                S1 = fmaf(m, uv.x, S1);
                S0 = fmaf(m * m, uv.y, S0);
            }
            wcos[((size_t)chunk * T_DIM + t) * WSTRIDE + item] =
                (s_G[p] + i2f(f2i(0.25f * S1) ^ svb) + 0.015625f * S0) * 0.0078125f;
        }
    } else {
        // ---- repack {C, A}; chunk-local max per p ----
        {
            const float ns = sqrtf(ss);
            const float csp = s_cspT[p][jl];
            const float b = s_css[jl] - csp;
            const float A = ns * sqrtf(s_nn[jl]) * (0.125f * LOG2E);
            const float z2 = fmaf(b, A, (j0 + jl) ? CORR_L2 : 0.0f);
            ((int2*)&s_pc4[jl * TP + p])[1] = make_int2(f2i(z2), f2i(A));
            float mloc = z2 + A;                     // max over the wave's 8 jl
            mloc = fmaxf(mloc, __shfl_xor(mloc, 8));
            mloc = fmaxf(mloc, __shfl_xor(mloc, 16));
            mloc = fmaxf(mloc, __shfl_xor(mloc, 32));
            if (lane < 8) s_Mpart[w][lane] = mloc;
        }
        __syncthreads();
        const float M = fmaxf(fmaxf(s_Mpart[0][p], s_Mpart[1][p]),
                              fmaxf(s_Mpart[2][p], s_Mpart[3][p]));
        if (tid < 8) wM[((size_t)chunk * T_DIM + t) * TP + tid] =
            fmaxf(fmaxf(s_Mpart[0][tid], s_Mpart[1][tid]),
                  fmaxf(s_Mpart[2][tid], s_Mpart[3][tid]));

        // ---- partial logsumexp over this chunk's 32 j ----
        for (int item = tid; item < WSTRIDE; item += BLOCK) {   // p = tid&7 inv.
            const int c = item >> 3;
            const int v = cand_v(c, sta, s_rand, p);
            const int va = v < 0 ? -v : v;
            const int vs = v & 0x80000000;
            float s0 = 0.f, s1 = 0.f;
            #pragma unroll 2
            for (int k = 0; k < CJ; k += 2) {
                const int4 X = s_pc4[k * TP + p];
                const int4 Y = s_pc4[(k + 1) * TP + p];
                s0 += __builtin_amdgcn_exp2f(CRO_Z(va, vs, X) - M);
                s1 += __builtin_amdgcn_exp2f(CRO_Z(va, vs, Y) - M);
            }
            wS[((size_t)chunk * T_DIM + t) * WSTRIDE + item] = s0 + s1;
            if (chunk == 0) {
                const int4 X0 = s_pc4[p];            // global j = 0
                wz0[(size_t)t * WSTRIDE + item] = CRO_Z(va, vs, X0);
            }
        }
    }
}

// -------- kernel B: merge chunks + argmin (first-min) + gather + means -------
__global__ void cg_combine(
    const int* __restrict__ sta_loc,
    const int* __restrict__ rand_masks,
    const float* __restrict__ wcos,
    const float* __restrict__ wS,
    const float* __restrict__ wM,
    const float* __restrict__ wz0,
    float* __restrict__ out)
{
    const int t = blockIdx.x;
    const int tid = threadIdx.x;        // 64
    const int p = tid & 7, cg = tid >> 3;

    // hoist chunk maxima for this p (candidate-independent)
    const float M0 = wM[((size_t)0 * T_DIM + t) * TP + p];
    const float M1 = wM[((size_t)1 * T_DIM + t) * TP + p];
    const float M2 = wM[((size_t)2 * T_DIM + t) * TP + p];
    const float M3 = wM[((size_t)3 * T_DIM + t) * TP + p];
    const float Ms = fmaxf(fmaxf(M0, M1), fmaxf(M2, M3));
    const float e0 = __builtin_amdgcn_exp2f(M0 - Ms);
    const float e1 = __builtin_amdgcn_exp2f(M1 - Ms);
    const float e2 = __builtin_amdgcn_exp2f(M2 - Ms);
    const float e3 = __builtin_amdgcn_exp2f(M3 - Ms);

    float best = INFINITY, blc = 0.f, blr = 0.f;
    int bc = NC;
    for (int c = cg; c < NC; c += 8) {  // ascending c: strict < keeps first-min
        const size_t idx = (size_t)t * WSTRIDE + c * TP + p;
        const size_t cs = (size_t)T_DIM * WSTRIDE;
        const float lc = wcos[idx] + wcos[cs + idx]
                       + wcos[2 * cs + idx] + wcos[3 * cs + idx];
        const float S = wS[idx] * e0 + wS[cs + idx] * e1
                      + wS[2 * cs + idx] * e2 + wS[3 * cs + idx] * e3;
        const float lr = (__builtin_amdgcn_logf(fmaxf(S, 1e-38f))
                          + Ms - wz0[idx]) * LN2;
        const float lt = fmaf(0.1f, lr, lc);
        if (lt < best) { best = lt; bc = c; blc = lc; blr = lr; }
    }
    // reduce across the 8 cg-lanes sharing p; tie -> smallest c (first-min)
    #pragma unroll
    for (int d = 8; d < 64; d <<= 1) {
        const float o_best = __shfl_xor(best, d);
        const float o_blc  = __shfl_xor(blc, d);
        const float o_blr  = __shfl_xor(blr, d);
        const int   o_bc   = __shfl_xor(bc, d);
        if (o_best < best || (o_best == best && o_bc < bc)) {
            best = o_best; bc = o_bc; blc = o_blc; blr = o_blr;
        }
    }

    float vc = 0.f, vr = 0.f, vt = 0.f;
    if (tid < TP) {
        const int sta = sta_loc[t * TP + tid];
        out[t * TP + tid] = (float)cand_v(bc, sta, rand_masks + t * 256, tid);
        vc = blc; vr = blr; vt = best;
    }
    vc += __shfl_xor(vc, 1); vc += __shfl_xor(vc, 2); vc += __shfl_xor(vc, 4);
    vr += __shfl_xor(vr, 1); vr += __shfl_xor(vr, 2); vr += __shfl_xor(vr, 4);
    vt += __shfl_xor(vt, 1); vt += __shfl_xor(vt, 2); vt += __shfl_xor(vt, 4);
    if (tid == 0) {
        out[T_DIM * TP + t] = vc * 0.125f;
        out[T_DIM * TP + T_DIM + t] = vr * 0.125f;
        out[T_DIM * TP + 2 * T_DIM + t] = vt * 0.125f;
    }
}

extern "C" void kernel_launch(void* const* d_in, const int* in_sizes, int n_in,
                              void* d_out, int out_size, void* d_ws, size_t ws_size,
                              hipStream_t stream) {
    const int* sta_loc = (const int*)d_in[0];
    const int* nei_loc = (const int*)d_in[1];
    const int* voc_loc = (const int*)d_in[2];
    const float* sta_emb = (const float*)d_in[3];
    const float* nei_emb = (const float*)d_in[4];
    const float* voc_emb = (const float*)d_in[5];
    const int* rand_masks = (const int*)d_in[6];
    float* out = (float*)d_out;

    // workspace: 4.26 + 4.26 + 0.06 + 1.06 MB ~= 9.7 MB
    float* wcos = (float*)d_ws;
    float* wS   = wcos + (size_t)NCH * T_DIM * WSTRIDE;
    float* wM   = wS   + (size_t)NCH * T_DIM * WSTRIDE;
    float* wz0  = wM   + (size_t)NCH * T_DIM * TP;

    cg_chunk<<<NCH * 2 * T_DIM, BLOCK, 0, stream>>>(
        sta_loc, nei_loc, voc_loc, sta_emb, nei_emb, voc_emb, rand_masks,
        wcos, wS, wM, wz0);
    cg_combine<<<T_DIM, 64, 0, stream>>>(
        sta_loc, rand_masks, wcos, wS, wM, wz0, out);
}